// Round 1
// baseline (17.499 us; speedup 1.0000x reference)
//
#include <hip/hip_runtime.h>
#include <math.h>

#define BB 256
#define DD 12288
#define LL 32
#define NPX 1024                 // log_px blocks: 4 per row
#define LOG2PI_F 1.8378770664093453f
#define BETA_F 6.0f

// ws layout: [0 .. NPX-1]    = log_px quarter-row partials
//            [NPX .. NPX+255] = per-i pairwise term t[i]

__global__ __launch_bounds__(256) void tcvae_main(
    const float* __restrict__ target,
    const float* __restrict__ x_mean,
    const float* __restrict__ x_log_var,
    const float* __restrict__ z,
    const float* __restrict__ z_mean,
    const float* __restrict__ z_log_var,
    float* __restrict__ ws, float log_nm)
{
    const int tid = threadIdx.x;
    const int bid = blockIdx.x;

    __shared__ float sd2[LL];
    __shared__ float vbuf[LL][257];   // M[i, j, l] cache: vbuf[l][j]
    __shared__ float red[8];
    __shared__ float lse_l[LL];
    __shared__ float misc[2];

    if (bid < NPX) {
        // ---- log_px quarter-row: row = bid>>2, quarter = bid&3 (3072 elems) ----
        const int row = bid >> 2;
        const int q   = bid & 3;
        const float4* t4 = (const float4*)target    + (size_t)row * (DD/4) + q * (DD/16);
        const float4* m4 = (const float4*)x_mean    + (size_t)row * (DD/4) + q * (DD/16);
        const float4* v4 = (const float4*)x_log_var + (size_t)row * (DD/4) + q * (DD/16);
        float acc = 0.f;
        #pragma unroll
        for (int it = 0; it < 3; ++it) {
            const int idx = it * 256 + tid;
            float4 x  = t4[idx];
            float4 m  = m4[idx];
            float4 lv = v4[idx];
            float dx;
            dx = x.x - m.x; acc += lv.x + dx * dx * __expf(-lv.x);
            dx = x.y - m.y; acc += lv.y + dx * dx * __expf(-lv.y);
            dx = x.z - m.z; acc += lv.z + dx * dx * __expf(-lv.z);
            dx = x.w - m.w; acc += lv.w + dx * dx * __expf(-lv.w);
        }
        // reduce sum over block
        #pragma unroll
        for (int o = 32; o; o >>= 1) acc += __shfl_xor(acc, o, 64);
        const int wid = tid >> 6, lane = tid & 63;
        if (lane == 0) red[wid] = acc;
        __syncthreads();
        if (tid == 0) {
            float s = red[0] + red[1] + red[2] + red[3];
            ws[bid] = -0.5f * ((float)(DD / 4) * LOG2PI_F + s);
        }
    } else {
        // ---- pairwise block for sample i ----
        const int i = bid - NPX;

        // lanes 0..31 of wave 0: d2[i,l], log_pz[i], log_qzx[i]
        if (tid < 64) {
            float pz = 0.f, qzx = 0.f;
            if (tid < LL) {
                float zl  = z[i * LL + tid];
                float zm  = z_mean[i * LL + tid];
                float lvi = z_log_var[i * LL + tid];
                float d   = zl - zm;
                float d2  = d * d;
                sd2[tid]  = d2;
                pz  = -0.5f * (LOG2PI_F + zl * zl);
                qzx = -0.5f * (LOG2PI_F + lvi + d2 * __expf(-lvi));
            }
            #pragma unroll
            for (int o = 32; o; o >>= 1) {
                pz  += __shfl_xor(pz,  o, 64);
                qzx += __shfl_xor(qzx, o, 64);
            }
            if (tid == 0) { misc[0] = pz; misc[1] = qzx; }
        }
        __syncthreads();

        // thread j computes M[i,j,l] for l=0..31, caches in vbuf, sums s_j
        const int j = tid;
        const float4* lv4 = (const float4*)(z_log_var + j * LL);
        float s_j = 0.f;
        #pragma unroll
        for (int qq = 0; qq < 8; ++qq) {
            float4 lv = lv4[qq];
            const int l0 = qq * 4;
            float A, e, v;
            A = -0.5f * (LOG2PI_F + lv.x); e = __expf(-lv.x);
            v = A - 0.5f * sd2[l0 + 0] * e; vbuf[l0 + 0][j] = v; s_j += v;
            A = -0.5f * (LOG2PI_F + lv.y); e = __expf(-lv.y);
            v = A - 0.5f * sd2[l0 + 1] * e; vbuf[l0 + 1][j] = v; s_j += v;
            A = -0.5f * (LOG2PI_F + lv.z); e = __expf(-lv.z);
            v = A - 0.5f * sd2[l0 + 2] * e; vbuf[l0 + 2][j] = v; s_j += v;
            A = -0.5f * (LOG2PI_F + lv.w); e = __expf(-lv.w);
            v = A - 0.5f * sd2[l0 + 3] * e; vbuf[l0 + 3][j] = v; s_j += v;
        }
        __syncthreads();   // vbuf complete

        // block-wide LSE over j of s_j  -> log_qz
        float mx = s_j;
        #pragma unroll
        for (int o = 32; o; o >>= 1) mx = fmaxf(mx, __shfl_xor(mx, o, 64));
        const int wid = tid >> 6, lane = tid & 63;
        if (lane == 0) red[wid] = mx;
        __syncthreads();
        mx = fmaxf(fmaxf(red[0], red[1]), fmaxf(red[2], red[3]));
        float es = __expf(s_j - mx);
        #pragma unroll
        for (int o = 32; o; o >>= 1) es += __shfl_xor(es, o, 64);
        if (lane == 0) red[4 + wid] = es;
        __syncthreads();
        const float log_qz = mx + logf(red[4] + red[5] + red[6] + red[7]) - log_nm;

        // per-l LSE over j: 8 threads per l, 32 j's each
        const int l = tid >> 3;
        const int k = tid & 7;
        float vals[32];
        float m2 = -INFINITY;
        #pragma unroll
        for (int mm = 0; mm < 32; ++mm) {
            float v = vbuf[l][k + 8 * mm];
            vals[mm] = v;
            m2 = fmaxf(m2, v);
        }
        #pragma unroll
        for (int o = 4; o; o >>= 1) m2 = fmaxf(m2, __shfl_xor(m2, o, 64));
        float se = 0.f;
        #pragma unroll
        for (int mm = 0; mm < 32; ++mm) se += __expf(vals[mm] - m2);
        #pragma unroll
        for (int o = 4; o; o >>= 1) se += __shfl_xor(se, o, 64);
        if (k == 0) lse_l[l] = m2 + logf(se);
        __syncthreads();

        if (tid < 64) {
            float v = (tid < LL) ? lse_l[tid] : 0.f;
            #pragma unroll
            for (int o = 32; o; o >>= 1) v += __shfl_xor(v, o, 64);
            if (tid == 0) {
                const float log_qz_prod = v - (float)LL * log_nm;
                // t[i] = log_pz - log_qzx + (1-B)*log_qz + (B-1)*log_qz_prod
                const float t = misc[0] - misc[1]
                              + (1.f - BETA_F) * log_qz
                              + (BETA_F - 1.f) * log_qz_prod;
                ws[NPX + i] = t;
            }
        }
    }
}

__global__ __launch_bounds__(256) void tcvae_final(
    const float* __restrict__ ws, float* __restrict__ out)
{
    const int tid = threadIdx.x;
    float v = ws[4 * tid] + ws[4 * tid + 1] + ws[4 * tid + 2] + ws[4 * tid + 3]
            + ws[NPX + tid];
    #pragma unroll
    for (int o = 32; o; o >>= 1) v += __shfl_xor(v, o, 64);
    __shared__ float red[4];
    const int wid = tid >> 6, lane = tid & 63;
    if (lane == 0) red[wid] = v;
    __syncthreads();
    if (tid == 0) out[0] = -(red[0] + red[1] + red[2] + red[3]) * (1.0f / (float)BB);
}

extern "C" void kernel_launch(void* const* d_in, const int* in_sizes, int n_in,
                              void* d_out, int out_size, void* d_ws, size_t ws_size,
                              hipStream_t stream) {
    const float* target    = (const float*)d_in[0];
    const float* x_mean    = (const float*)d_in[1];
    const float* x_log_var = (const float*)d_in[2];
    const float* z         = (const float*)d_in[3];
    const float* z_mean    = (const float*)d_in[4];
    const float* z_log_var = (const float*)d_in[5];
    float* ws  = (float*)d_ws;
    float* out = (float*)d_out;

    const float log_nm = logf((float)BB * 202599.0f);

    tcvae_main<<<NPX + BB, 256, 0, stream>>>(target, x_mean, x_log_var,
                                             z, z_mean, z_log_var, ws, log_nm);
    tcvae_final<<<1, 256, 0, stream>>>(ws, out);
}

// Round 2
// 15.270 us; speedup vs baseline: 1.1460x; 1.1460x over previous
//
#include <hip/hip_runtime.h>
#include <math.h>

#define BB 256
#define DD 12288
#define LL 32
#define NPX 3072                 // log_px blocks: flat partition, 1024 elems each
#define LOG2PI_F 1.8378770664093453f
#define BETA_F 6.0f

// ws layout: [0 .. NPX-1]        = log_px flat partial sums of (lv + dx^2*e^-lv)
//            [NPX .. NPX+255]    = per-i pairwise term t[i]

__global__ __launch_bounds__(256) void tcvae_main(
    const float* __restrict__ target,
    const float* __restrict__ x_mean,
    const float* __restrict__ x_log_var,
    const float* __restrict__ z,
    const float* __restrict__ z_mean,
    const float* __restrict__ z_log_var,
    float* __restrict__ ws, float log_nm)
{
    const int tid = threadIdx.x;
    const int bid = blockIdx.x;

    if (bid >= BB) {
        // ---- log_px flat chunk: 256 threads x 1 float4 per array ----
        const size_t g = (size_t)(bid - BB) * 256 + tid;
        float4 x  = ((const float4*)target)[g];
        float4 m  = ((const float4*)x_mean)[g];
        float4 lv = ((const float4*)x_log_var)[g];
        float dx, acc = 0.f;
        dx = x.x - m.x; acc += lv.x + dx * dx * __expf(-lv.x);
        dx = x.y - m.y; acc += lv.y + dx * dx * __expf(-lv.y);
        dx = x.z - m.z; acc += lv.z + dx * dx * __expf(-lv.z);
        dx = x.w - m.w; acc += lv.w + dx * dx * __expf(-lv.w);
        // block reduce
        #pragma unroll
        for (int o = 32; o; o >>= 1) acc += __shfl_xor(acc, o, 64);
        __shared__ float red[4];
        const int wid = tid >> 6, lane = tid & 63;
        if (lane == 0) red[wid] = acc;
        __syncthreads();
        if (tid == 0) ws[bid - BB] = red[0] + red[1] + red[2] + red[3];
        return;
    }

    // ---- pairwise block for sample i ----
    const int i = bid;

    __shared__ float sd2[LL];
    __shared__ float vbuf[LL][257];   // M[i, j, l] cache: vbuf[l][j]
    __shared__ float red[8];
    __shared__ float lse_l[LL];
    __shared__ float misc[2];

    // lanes 0..31 of wave 0: d2[i,l], log_pz[i], log_qzx[i]
    if (tid < 64) {
        float pz = 0.f, qzx = 0.f;
        if (tid < LL) {
            float zl  = z[i * LL + tid];
            float zm  = z_mean[i * LL + tid];
            float lvi = z_log_var[i * LL + tid];
            float d   = zl - zm;
            float d2  = d * d;
            sd2[tid]  = d2;
            pz  = -0.5f * (LOG2PI_F + zl * zl);
            qzx = -0.5f * (LOG2PI_F + lvi + d2 * __expf(-lvi));
        }
        #pragma unroll
        for (int o = 32; o; o >>= 1) {
            pz  += __shfl_xor(pz,  o, 64);
            qzx += __shfl_xor(qzx, o, 64);
        }
        if (tid == 0) { misc[0] = pz; misc[1] = qzx; }
    }
    __syncthreads();

    // thread j computes M[i,j,l] for l=0..31, caches in vbuf, sums s_j
    const int j = tid;
    const float4* lv4 = (const float4*)(z_log_var + j * LL);
    float s_j = 0.f;
    #pragma unroll
    for (int qq = 0; qq < 8; ++qq) {
        float4 lv = lv4[qq];
        const int l0 = qq * 4;
        float A, e, v;
        A = -0.5f * (LOG2PI_F + lv.x); e = __expf(-lv.x);
        v = A - 0.5f * sd2[l0 + 0] * e; vbuf[l0 + 0][j] = v; s_j += v;
        A = -0.5f * (LOG2PI_F + lv.y); e = __expf(-lv.y);
        v = A - 0.5f * sd2[l0 + 1] * e; vbuf[l0 + 1][j] = v; s_j += v;
        A = -0.5f * (LOG2PI_F + lv.z); e = __expf(-lv.z);
        v = A - 0.5f * sd2[l0 + 2] * e; vbuf[l0 + 2][j] = v; s_j += v;
        A = -0.5f * (LOG2PI_F + lv.w); e = __expf(-lv.w);
        v = A - 0.5f * sd2[l0 + 3] * e; vbuf[l0 + 3][j] = v; s_j += v;
    }
    __syncthreads();   // vbuf complete

    // block-wide LSE over j of s_j  -> log_qz
    float mx = s_j;
    #pragma unroll
    for (int o = 32; o; o >>= 1) mx = fmaxf(mx, __shfl_xor(mx, o, 64));
    const int wid = tid >> 6, lane = tid & 63;
    if (lane == 0) red[wid] = mx;
    __syncthreads();
    mx = fmaxf(fmaxf(red[0], red[1]), fmaxf(red[2], red[3]));
    float es = __expf(s_j - mx);
    #pragma unroll
    for (int o = 32; o; o >>= 1) es += __shfl_xor(es, o, 64);
    if (lane == 0) red[4 + wid] = es;
    __syncthreads();
    const float log_qz = mx + logf(red[4] + red[5] + red[6] + red[7]) - log_nm;

    // per-l LSE over j: 8 threads per l, 32 j's each
    const int l = tid >> 3;
    const int k = tid & 7;
    float vals[32];
    float m2 = -INFINITY;
    #pragma unroll
    for (int mm = 0; mm < 32; ++mm) {
        float v = vbuf[l][k + 8 * mm];
        vals[mm] = v;
        m2 = fmaxf(m2, v);
    }
    #pragma unroll
    for (int o = 4; o; o >>= 1) m2 = fmaxf(m2, __shfl_xor(m2, o, 64));
    float se = 0.f;
    #pragma unroll
    for (int mm = 0; mm < 32; ++mm) se += __expf(vals[mm] - m2);
    #pragma unroll
    for (int o = 4; o; o >>= 1) se += __shfl_xor(se, o, 64);
    if (k == 0) lse_l[l] = m2 + logf(se);
    __syncthreads();

    if (tid < 64) {
        float v = (tid < LL) ? lse_l[tid] : 0.f;
        #pragma unroll
        for (int o = 32; o; o >>= 1) v += __shfl_xor(v, o, 64);
        if (tid == 0) {
            const float log_qz_prod = v - (float)LL * log_nm;
            // t[i] = log_pz - log_qzx + (1-B)*log_qz + (B-1)*log_qz_prod
            const float t = misc[0] - misc[1]
                          + (1.f - BETA_F) * log_qz
                          + (BETA_F - 1.f) * log_qz_prod;
            ws[NPX + i] = t;
        }
    }
}

__global__ __launch_bounds__(256) void tcvae_final(
    const float* __restrict__ ws, float* __restrict__ out)
{
    const int tid = threadIdx.x;
    // px partials: 3072 floats = 768 float4; 256 threads x 3 float4
    const float4* w4 = (const float4*)ws;
    float v = 0.f;
    #pragma unroll
    for (int q = 0; q < 3; ++q) {
        float4 w = w4[tid + 256 * q];
        v += w.x + w.y + w.z + w.w;
    }
    // v holds chunk of S_px; pairwise term separately
    float t = ws[NPX + tid];
    #pragma unroll
    for (int o = 32; o; o >>= 1) {
        v += __shfl_xor(v, o, 64);
        t += __shfl_xor(t, o, 64);
    }
    __shared__ float red[8];
    const int wid = tid >> 6, lane = tid & 63;
    if (lane == 0) { red[wid] = v; red[4 + wid] = t; }
    __syncthreads();
    if (tid == 0) {
        const float S_px = red[0] + red[1] + red[2] + red[3];
        const float T    = red[4] + red[5] + red[6] + red[7];
        const float log_px_sum = -0.5f * ((float)BB * (float)DD * LOG2PI_F + S_px);
        out[0] = -(log_px_sum + T) * (1.0f / (float)BB);
    }
}

extern "C" void kernel_launch(void* const* d_in, const int* in_sizes, int n_in,
                              void* d_out, int out_size, void* d_ws, size_t ws_size,
                              hipStream_t stream) {
    const float* target    = (const float*)d_in[0];
    const float* x_mean    = (const float*)d_in[1];
    const float* x_log_var = (const float*)d_in[2];
    const float* z         = (const float*)d_in[3];
    const float* z_mean    = (const float*)d_in[4];
    const float* z_log_var = (const float*)d_in[5];
    float* ws  = (float*)d_ws;
    float* out = (float*)d_out;

    const float log_nm = logf((float)BB * 202599.0f);

    tcvae_main<<<BB + NPX, 256, 0, stream>>>(target, x_mean, x_log_var,
                                             z, z_mean, z_log_var, ws, log_nm);
    tcvae_final<<<1, 256, 0, stream>>>(ws, out);
}